// Round 7
// baseline (318.276 us; speedup 1.0000x reference)
//
#include <hip/hip_runtime.h>
#include <math.h>

#define B_ 8
#define U_ 512
#define T_ 1024
#define H_ 512
#define D_ 128
#define K_ 10

#define UT 8      // u rows per attend block / scan tile size
#define TC 32     // t chunk size
#define NTILES 64 // U_/UT

// CALIBRATION BUILD: both kernels repeat their hot section 16x (results
// identical -- only the last rep is kept; asm fences stop hoisting/DCE).
// Purpose: lift both kernels above the harness fillBuffer dispatches (~40us)
// so rocprof top-5 shows their true counters; real time ~= dur/16.
#define PREP_REP 16
#define AT_REP 16

// ---------------- Kernel A: params (split-H) + tile-local kappa scan --------
__global__ __launch_bounds__(512)
void prep_kernel(const float* __restrict__ h_t,
                 const float* __restrict__ W,
                 const float* __restrict__ bias,
                 float* __restrict__ alpha,
                 float* __restrict__ beta,
                 float* __restrict__ L,
                 float* __restrict__ T) {
    __shared__ float part_s[8][30][2];
    __shared__ float kin_s[8][K_];

    int tid = threadIdx.x;
    int lane = tid & 63;
    int w = tid >> 6;               // 0..7
    int q = w >> 1;                 // row-pair 0..3
    int hs = w & 1;                 // H-half 0/1
    int j = lane & 31;              // col (j<30 active)
    int s = lane >> 5;              // row within pair
    int rloc = q * 2 + s;           // 0..7
    int row = blockIdx.x * 8 + rloc;
    int jj = (j < 30) ? j : 29;

    const float4* hp = (const float4*)(h_t + (size_t)row * H_ + hs * (H_ / 2));
    const float* wp0 = W + (size_t)(hs * (H_ / 2)) * (3 * K_) + jj;

    float acc = 0.f;
    for (int rep = 0; rep < PREP_REP; ++rep) {
        const float4* hp_r = hp;
        const float* wp_r = wp0;
        asm volatile("" : "+v"(hp_r), "+v"(wp_r));   // opaque per-rep bases
        float a2 = 0.f;
        #pragma unroll 8
        for (int i4 = 0; i4 < (H_ / 2) / 4; ++i4) {
            float4 h4 = hp_r[i4];
            const float* wp = wp_r + (size_t)(4 * i4) * (3 * K_);
            a2 += h4.x * wp[0] + h4.y * wp[30] + h4.z * wp[60] + h4.w * wp[90];
        }
        asm volatile("" : "+v"(a2));                 // keep every rep live
        acc = a2;
    }

    if (j < 30) part_s[rloc][j][hs] = acc;
    __syncthreads();

    if (tid < 240) {
        int r = tid / 30, c = tid % 30;
        float p = __expf(part_s[r][c][0] + part_s[r][c][1] + bias[c]);
        int row2 = blockIdx.x * 8 + r;
        if (c < 10)      alpha[(size_t)row2 * K_ + c] = p;
        else if (c < 20) beta[(size_t)row2 * K_ + (c - 10)] = p;
        else             kin_s[r][c - 20] = 0.2f * p;
    }
    __syncthreads();

    if (tid < UT * K_) {
        int u_l = tid / K_, k = tid % K_;
        float ssum = 0.f;
        for (int r = 0; r <= u_l; ++r) ssum += kin_s[r][k];
        int urow = blockIdx.x * 8 + u_l;
        L[(size_t)urow * K_ + k] = ssum;
        if (u_l == UT - 1) {
            int b = urow >> 9;
            int tile = (urow & (U_ - 1)) >> 3;
            T[((size_t)b * NTILES + tile) * K_ + k] = ssum;
        }
    }
}

// ---------------- Kernel B: prefix combine + phi + masked matmul ------------
__global__ __launch_bounds__(256)
void attend_kernel(const float* __restrict__ alpha,
                   const float* __restrict__ beta,
                   const float* __restrict__ L,
                   const float* __restrict__ T,
                   const float* __restrict__ ctx,
                   const float* __restrict__ mask,
                   float* __restrict__ out) {
    __shared__ float a_s[UT][K_], b_s[UT][K_], k_s[UT][K_];
    __shared__ float phi_s[UT][TC + 4];
    __shared__ float ctx_s[TC][D_];
    __shared__ float red_lo[256], red_hi[256];

    int tid = threadIdx.x;
    int b = blockIdx.x >> 6;
    int mytile = blockIdx.x & 63;
    int u0 = mytile * UT;

    float lo = 1e30f, hi = -1e30f;
    if (tid < UT * K_) {
        int u_l = tid / K_, k = tid % K_;
        size_t idx = ((size_t)(b * U_) + u0 + u_l) * K_ + k;
        float pre = 0.f;
        const float* tp = T + ((size_t)b * NTILES) * K_ + k;
        for (int jt = 0; jt < mytile; ++jt) pre += tp[(size_t)jt * K_];
        float kv = pre + L[idx];
        float av = alpha[idx], bvv = beta[idx];
        a_s[u_l][k] = av; b_s[u_l][k] = bvv; k_s[u_l][k] = kv;
        float r = sqrtf(88.f / bvv);
        lo = kv - r; hi = kv + r;
    }
    red_lo[tid] = lo; red_hi[tid] = hi;
    __syncthreads();
    for (int s = 128; s > 0; s >>= 1) {
        if (tid < s) {
            red_lo[tid] = fminf(red_lo[tid], red_lo[tid + s]);
            red_hi[tid] = fmaxf(red_hi[tid], red_hi[tid + s]);
        }
        __syncthreads();
    }
    int t_begin = max(0, (int)floorf(red_lo[0]));
    int t_end   = min(T_, (int)ceilf(red_hi[0]) + 1);
    t_begin = (t_begin / TC) * TC;

    int u_l = tid >> 5;
    int g   = tid & 31;
    float accv[4] = {0.f, 0.f, 0.f, 0.f};

    for (int rep = 0; rep < AT_REP; ++rep) {
        float a0 = 0.f, a1 = 0.f, a2 = 0.f, a3 = 0.f;
        for (int t0 = t_begin; t0 < t_end; t0 += TC) {
            __syncthreads();
            {
                const float4* src = (const float4*)(ctx + (((size_t)b * T_ + t0) * D_));
                float4* dst = (float4*)(&ctx_s[0][0]);
                #pragma unroll
                for (int i = 0; i < (TC * D_ / 4) / 256; ++i)
                    dst[tid + 256 * i] = src[tid + 256 * i];
            }
            {
                int uu = tid >> 5;
                int tl = tid & 31;
                float tf = (float)(t0 + tl);
                float ph = 0.f;
                #pragma unroll
                for (int k = 0; k < K_; ++k) {
                    float d = k_s[uu][k] - tf;
                    float x = b_s[uu][k] * d * d;
                    ph += a_s[uu][k] * __expf(-x);
                }
                phi_s[uu][tl] = ph * mask[(size_t)b * T_ + t0 + tl];
            }
            __syncthreads();
            for (int tl4 = 0; tl4 < TC / 4; ++tl4) {
                float4 ph4 = *(const float4*)(&phi_s[u_l][4 * tl4]);
                #pragma unroll
                for (int qq = 0; qq < 4; ++qq) {
                    float ph = (qq == 0) ? ph4.x : (qq == 1) ? ph4.y : (qq == 2) ? ph4.z : ph4.w;
                    float4 c0 = ((const float4*)(&ctx_s[4 * tl4 + qq][0]))[g];
                    a0 += ph * c0.x; a1 += ph * c0.y;
                    a2 += ph * c0.z; a3 += ph * c0.w;
                }
            }
        }
        asm volatile("" : "+v"(a0), "+v"(a1), "+v"(a2), "+v"(a3));  // keep rep live
        accv[0] = a0; accv[1] = a1; accv[2] = a2; accv[3] = a3;
    }

    float* orow = out + ((size_t)b * U_ + u0 + u_l) * D_;
    *(float4*)(orow + 4 * g) = make_float4(accv[0], accv[1], accv[2], accv[3]);
}

extern "C" void kernel_launch(void* const* d_in, const int* in_sizes, int n_in,
                              void* d_out, int out_size, void* d_ws, size_t ws_size,
                              hipStream_t stream) {
    const float* h_t  = (const float*)d_in[0];
    const float* ctx  = (const float*)d_in[1];
    const float* mask = (const float*)d_in[2];
    const float* W    = (const float*)d_in[3];
    const float* bias = (const float*)d_in[4];
    float* out = (float*)d_out;

    const size_t NPARAM = (size_t)B_ * U_ * K_;
    float* alpha = (float*)d_ws;
    float* beta  = alpha + NPARAM;
    float* L     = beta + NPARAM;
    float* T     = L + NPARAM;

    prep_kernel<<<dim3(512), dim3(512), 0, stream>>>(h_t, W, bias, alpha, beta, L, T);
    attend_kernel<<<dim3(512), dim3(256), 0, stream>>>(alpha, beta, L, T, ctx, mask, out);
}

// Round 8
// 25.247 us; speedup vs baseline: 12.6066x; 12.6066x over previous
//
#include <hip/hip_runtime.h>
#include <math.h>

#define B_ 8
#define U_ 512
#define T_ 1024
#define H_ 512
#define D_ 128
#define K_ 10

#define UT 8      // u rows per attend block / scan tile size
#define TC 32     // t chunk size
#define NTILES 64 // U_/UT

typedef __attribute__((ext_vector_type(8))) short bf16x8;
typedef __attribute__((ext_vector_type(4))) float f32x4;

__device__ __forceinline__ unsigned short f32_to_bf16_rtne(float f) {
    unsigned u = __float_as_uint(f);
    unsigned r = u + 0x7FFFu + ((u >> 16) & 1u);
    return (unsigned short)(r >> 16);
}
__device__ __forceinline__ unsigned pack_bf16(float a, float b) {
    return (unsigned)f32_to_bf16_rtne(a) | ((unsigned)f32_to_bf16_rtne(b) << 16);
}

// ---------------- Kernel A: params GEMM via MFMA + tile-local kappa scan ----
// Grid 256 blocks x 256 threads (4 waves). Block = 16 rows (M-tile).
// C[16][32] = A[16][512]_bf16 x W'[512][32]_bf16 (cols 30,31 zero-padded).
// Wave w: khalf=w>>1 (K range of 256), ntile=w&1 (16-col N-tile).
// B-fragments: 8 per wave, held in VGPRs, loaded once from W (L2-resident).
// A staged f32->bf16 into XOR-swizzled LDS (conflict-free ds_read_b128).
// MFMA 16x16x32_bf16: A-frag lane l: row=l&15, k=(l>>4)*8+e.
//                     B-frag lane l: col=l&15, k=(l>>4)*8+e.
//                     C/D  lane l: col=l&15, row=(l>>4)*4+reg  [m89-verified].
__global__ __launch_bounds__(256)
void prep_kernel(const float* __restrict__ h_t,
                 const float* __restrict__ W,
                 const float* __restrict__ bias,
                 float* __restrict__ alpha,
                 float* __restrict__ beta,
                 float* __restrict__ L,     // [B*U][K] tile-local inclusive sums
                 float* __restrict__ T) {   // [B][NTILES][K] tile totals
    __shared__ unsigned short A_s[16 * 512];   // 16 KB, XOR-swizzled rows
    __shared__ float Cp[2][16][33];            // K-half partials, +1 pad
    __shared__ float kin_s[16][K_];

    int tid = threadIdx.x;
    int lane = tid & 63;
    int w = tid >> 6;
    int khalf = w >> 1;
    int ntile = w & 1;
    int row0 = blockIdx.x * 16;

    // ---- B fragments (issued first; L2-hit latency hides under A staging)
    int c = 16 * ntile + (lane & 15);
    int kb = khalf * 256 + ((lane >> 4) << 3);
    bf16x8 bfrag[8];
    #pragma unroll
    for (int s = 0; s < 8; ++s) {
        #pragma unroll
        for (int e = 0; e < 8; ++e) {
            float wv = (c < 30) ? W[(size_t)(kb + 32 * s + e) * 30 + c] : 0.f;
            bfrag[s][e] = (short)f32_to_bf16_rtne(wv);
        }
    }

    // ---- stage A: thread t -> row r=t>>4, k-chunk kc=(t&15)*32 (coalesced)
    {
        int r = tid >> 4;
        int kc = (tid & 15) * 32;
        const float4* src = (const float4*)(h_t + (size_t)(row0 + r) * H_ + kc);
        unsigned pk[16];
        #pragma unroll
        for (int i = 0; i < 8; ++i) {
            float4 v = src[i];
            pk[2 * i]     = pack_bf16(v.x, v.y);
            pk[2 * i + 1] = pack_bf16(v.z, v.w);
        }
        int base = r * 1024 + kc * 2;       // byte offset in A_s
        int swz = (r & 7) << 4;
        #pragma unroll
        for (int m = 0; m < 4; ++m) {
            *(int4*)((char*)A_s + ((base + m * 16) ^ swz)) =
                make_int4((int)pk[4 * m], (int)pk[4 * m + 1],
                          (int)pk[4 * m + 2], (int)pk[4 * m + 3]);
        }
    }
    __syncthreads();

    // ---- MFMA: 8 K-steps accumulate into one C fragment
    {
        int ar = lane & 15;
        int abase = ar * 1024 + (khalf * 256 + ((lane >> 4) << 3)) * 2;
        int aswz = (ar & 7) << 4;
        f32x4 acc = {0.f, 0.f, 0.f, 0.f};
        #pragma unroll
        for (int s = 0; s < 8; ++s) {
            bf16x8 af = *(const bf16x8*)((const char*)A_s + ((abase + s * 64) ^ aswz));
            acc = __builtin_amdgcn_mfma_f32_16x16x32_bf16(af, bfrag[s], acc, 0, 0, 0);
        }
        int ccol = 16 * ntile + (lane & 15);
        #pragma unroll
        for (int r = 0; r < 4; ++r)
            Cp[khalf][(lane >> 4) * 4 + r][ccol] = acc[r];
    }
    __syncthreads();

    // ---- combine K-halves, exp, route (512 outputs, 2 per thread)
    #pragma unroll
    for (int i = 0; i < 2; ++i) {
        int o = tid + 256 * i;
        int rr = o >> 5, cc = o & 31;
        if (cc < 30) {
            float dot = Cp[0][rr][cc] + Cp[1][rr][cc];
            float p = __expf(dot + bias[cc]);
            int row2 = row0 + rr;
            if (cc < 10)      alpha[(size_t)row2 * K_ + cc] = p;
            else if (cc < 20) beta[(size_t)row2 * K_ + (cc - 10)] = p;
            else              kin_s[rr][cc - 20] = 0.2f * p;
        }
    }
    __syncthreads();

    // ---- tile-local inclusive scans over the block's two 8-row tiles
    if (tid < 16 * K_) {
        int u_l = tid / K_, k = tid % K_;
        int tb = u_l & ~(UT - 1);
        float ssum = 0.f;
        for (int r = tb; r <= u_l; ++r) ssum += kin_s[r][k];
        int urow = row0 + u_l;
        L[(size_t)urow * K_ + k] = ssum;
        if ((u_l & (UT - 1)) == (UT - 1)) {
            int b = urow >> 9;                  // /U_
            int tile = (urow & (U_ - 1)) >> 3;  // /UT
            T[((size_t)b * NTILES + tile) * K_ + k] = ssum;
        }
    }
}

// ---------------- Kernel B: prefix combine + phi + masked matmul ------------
// (byte-identical to R6: 512 blocks x 256 threads, TC=32)
__global__ __launch_bounds__(256)
void attend_kernel(const float* __restrict__ alpha,
                   const float* __restrict__ beta,
                   const float* __restrict__ L,
                   const float* __restrict__ T,
                   const float* __restrict__ ctx,
                   const float* __restrict__ mask,
                   float* __restrict__ out) {
    __shared__ float a_s[UT][K_], b_s[UT][K_], k_s[UT][K_];
    __shared__ float phi_s[UT][TC + 4];
    __shared__ float ctx_s[TC][D_];
    __shared__ float red_lo[256], red_hi[256];

    int tid = threadIdx.x;
    int b = blockIdx.x >> 6;
    int mytile = blockIdx.x & 63;
    int u0 = mytile * UT;

    float lo = 1e30f, hi = -1e30f;
    if (tid < UT * K_) {
        int u_l = tid / K_, k = tid % K_;
        size_t idx = ((size_t)(b * U_) + u0 + u_l) * K_ + k;
        float pre = 0.f;
        const float* tp = T + ((size_t)b * NTILES) * K_ + k;
        for (int jt = 0; jt < mytile; ++jt) pre += tp[(size_t)jt * K_];
        float kv = pre + L[idx];
        float av = alpha[idx], bvv = beta[idx];
        a_s[u_l][k] = av; b_s[u_l][k] = bvv; k_s[u_l][k] = kv;
        float r = sqrtf(88.f / bvv);
        lo = kv - r; hi = kv + r;
    }
    red_lo[tid] = lo; red_hi[tid] = hi;
    __syncthreads();
    for (int s = 128; s > 0; s >>= 1) {
        if (tid < s) {
            red_lo[tid] = fminf(red_lo[tid], red_lo[tid + s]);
            red_hi[tid] = fmaxf(red_hi[tid], red_hi[tid + s]);
        }
        __syncthreads();
    }
    int t_begin = max(0, (int)floorf(red_lo[0]));
    int t_end   = min(T_, (int)ceilf(red_hi[0]) + 1);
    t_begin = (t_begin / TC) * TC;

    int u_l = tid >> 5;
    int g   = tid & 31;
    float acc[4];
    #pragma unroll
    for (int i = 0; i < 4; ++i) acc[i] = 0.f;

    for (int t0 = t_begin; t0 < t_end; t0 += TC) {
        __syncthreads();
        {
            const float4* src = (const float4*)(ctx + (((size_t)b * T_ + t0) * D_));
            float4* dst = (float4*)(&ctx_s[0][0]);
            #pragma unroll
            for (int i = 0; i < (TC * D_ / 4) / 256; ++i)
                dst[tid + 256 * i] = src[tid + 256 * i];
        }
        {
            int uu = tid >> 5;
            int tl = tid & 31;
            float tf = (float)(t0 + tl);
            float ph = 0.f;
            #pragma unroll
            for (int k = 0; k < K_; ++k) {
                float d = k_s[uu][k] - tf;
                float x = b_s[uu][k] * d * d;
                ph += a_s[uu][k] * __expf(-x);
            }
            phi_s[uu][tl] = ph * mask[(size_t)b * T_ + t0 + tl];
        }
        __syncthreads();
        for (int tl4 = 0; tl4 < TC / 4; ++tl4) {
            float4 ph4 = *(const float4*)(&phi_s[u_l][4 * tl4]);
            #pragma unroll
            for (int qq = 0; qq < 4; ++qq) {
                float ph = (qq == 0) ? ph4.x : (qq == 1) ? ph4.y : (qq == 2) ? ph4.z : ph4.w;
                float4 c0 = ((const float4*)(&ctx_s[4 * tl4 + qq][0]))[g];
                acc[0] += ph * c0.x; acc[1] += ph * c0.y;
                acc[2] += ph * c0.z; acc[3] += ph * c0.w;
            }
        }
    }

    float* orow = out + ((size_t)b * U_ + u0 + u_l) * D_;
    *(float4*)(orow + 4 * g) = make_float4(acc[0], acc[1], acc[2], acc[3]);
}

extern "C" void kernel_launch(void* const* d_in, const int* in_sizes, int n_in,
                              void* d_out, int out_size, void* d_ws, size_t ws_size,
                              hipStream_t stream) {
    const float* h_t  = (const float*)d_in[0];
    const float* ctx  = (const float*)d_in[1];
    const float* mask = (const float*)d_in[2];
    const float* W    = (const float*)d_in[3];
    const float* bias = (const float*)d_in[4];
    float* out = (float*)d_out;

    const size_t NPARAM = (size_t)B_ * U_ * K_;       // 40960
    float* alpha = (float*)d_ws;
    float* beta  = alpha + NPARAM;
    float* L     = beta + NPARAM;
    float* T     = L + NPARAM;                        // B*NTILES*K = 5120

    prep_kernel<<<dim3(256), dim3(256), 0, stream>>>(h_t, W, bias, alpha, beta, L, T);
    attend_kernel<<<dim3(512), dim3(256), 0, stream>>>(alpha, beta, L, T, ctx, mask, out);
}

// Round 9
// 21.553 us; speedup vs baseline: 14.7672x; 1.1714x over previous
//
#include <hip/hip_runtime.h>
#include <math.h>

#define B_ 8
#define U_ 512
#define T_ 1024
#define H_ 512
#define D_ 128
#define K_ 10

#define UT 8      // u rows per block / scan tile size
#define TC 32     // t chunk size
#define NTILES 64 // U_/UT

typedef __attribute__((ext_vector_type(8))) short bf16x8;
typedef __attribute__((ext_vector_type(4))) float f32x4;

__device__ __forceinline__ unsigned short f32_to_bf16_rtne(float f) {
    unsigned u = __float_as_uint(f);
    unsigned r = u + 0x7FFFu + ((u >> 16) & 1u);
    return (unsigned short)(r >> 16);
}
__device__ __forceinline__ unsigned pack_bf16(float a, float b) {
    return (unsigned)f32_to_bf16_rtne(a) | ((unsigned)f32_to_bf16_rtne(b) << 16);
}

// ---------------- Fused kernel: prep (MFMA GEMM) + lookback + attend --------
// 512 blocks x 256 threads; block = (batch b, tile of 8 u-rows).
// Cross-block dep is ONLY the tile totals Tg[b][tile][k] (strictly positive):
// published via RELAXED agent atomic stores (value-is-flag, spin until >0).
// Co-residency (deadlock safety): LDS ~39KB (<=4 blk/CU), launch_bounds(256,2)
// caps VGPR<=128 => >=2 blocks/CU => all 512 blocks resident.
__global__ __launch_bounds__(256, 2)
void fused_kernel(const float* __restrict__ h_t,
                  const float* __restrict__ ctx,
                  const float* __restrict__ mask,
                  const float* __restrict__ W,
                  const float* __restrict__ bias,
                  float* __restrict__ out,
                  float* __restrict__ Tg) {   // [B][NTILES][K] tile totals
    __shared__ unsigned short A_s[16 * 512];   // 16 KB (rows 8-15 unwritten)
    __shared__ float Cp[2][8][33];             // K-half partials, +1 pad
    __shared__ float ab_s[8][20];              // alpha[k], beta[10+k]
    __shared__ float kin_s[8][K_];             // kinc, later kappa
    __shared__ float L_s[8][K_];               // tile-local inclusive sums
    __shared__ float part_s[16][K_];           // lookback partials
    __shared__ float pre_s[K_];
    __shared__ float phi_s[8][TC + 4];
    __shared__ float ctx_s[TC][D_];            // 16 KB
    __shared__ float red_lo[256], red_hi[256];

    int tid = threadIdx.x;
    int lane = tid & 63;
    int w = tid >> 6;
    int b = blockIdx.x >> 6;
    int mytile = blockIdx.x & 63;
    int row0 = b * U_ + mytile * UT;           // global h_t row of tile start

    // ---- B fragments: 8 per wave, held in VGPRs (W is L2-resident)
    int khalf = w >> 1;
    int ntile = w & 1;
    int c = 16 * ntile + (lane & 15);
    int kb = khalf * 256 + ((lane >> 4) << 3);
    bf16x8 bfrag[8];
    #pragma unroll
    for (int s = 0; s < 8; ++s) {
        #pragma unroll
        for (int e = 0; e < 8; ++e) {
            float wv = (c < 30) ? W[(size_t)(kb + 32 * s + e) * 30 + c] : 0.f;
            bfrag[s][e] = (short)f32_to_bf16_rtne(wv);
        }
    }

    // ---- stage A (8 rows): thread -> row r=t>>5, k-chunk (t&31)*16
    {
        int r = tid >> 5;
        int kc = (tid & 31) * 16;
        const float4* src = (const float4*)(h_t + (size_t)(row0 + r) * H_ + kc);
        unsigned pk[8];
        #pragma unroll
        for (int i = 0; i < 4; ++i) {
            float4 v = src[i];
            pk[2 * i]     = pack_bf16(v.x, v.y);
            pk[2 * i + 1] = pack_bf16(v.z, v.w);
        }
        int base = r * 1024 + kc * 2;          // byte offset
        int swz = (r & 7) << 4;
        *(int4*)((char*)A_s + ((base) ^ swz)) =
            make_int4((int)pk[0], (int)pk[1], (int)pk[2], (int)pk[3]);
        *(int4*)((char*)A_s + ((base + 16) ^ swz)) =
            make_int4((int)pk[4], (int)pk[5], (int)pk[6], (int)pk[7]);
    }
    __syncthreads();

    // ---- MFMA: M=16 tile, only rows 0-7 meaningful
    {
        int ar = lane & 15;
        int abase = ar * 1024 + (khalf * 256 + ((lane >> 4) << 3)) * 2;
        int aswz = (ar & 7) << 4;
        f32x4 acc = {0.f, 0.f, 0.f, 0.f};
        #pragma unroll
        for (int s = 0; s < 8; ++s) {
            bf16x8 af = *(const bf16x8*)((const char*)A_s + ((abase + s * 64) ^ aswz));
            acc = __builtin_amdgcn_mfma_f32_16x16x32_bf16(af, bfrag[s], acc, 0, 0, 0);
        }
        int rbase = (lane >> 4) * 4;           // C/D: col=lane&15, row=rbase+r
        if (rbase < 8) {
            int ccol = 16 * ntile + (lane & 15);
            #pragma unroll
            for (int r = 0; r < 4; ++r)
                Cp[khalf][rbase + r][ccol] = acc[r];
        }
    }
    __syncthreads();

    // ---- combine K-halves, exp, route (8x30 outputs)
    if (tid < 240) {
        int rr = tid / 30, cc = tid % 30;
        float p = __expf(Cp[0][rr][cc] + Cp[1][rr][cc] + bias[cc]);
        if (cc < 20) ab_s[rr][cc] = p;
        else         kin_s[rr][cc - 20] = 0.2f * p;
    }
    __syncthreads();

    // ---- tile-local scan + publish total; zero lookback partials
    if (tid < UT * K_) {
        int u_l = tid / K_, k = tid % K_;
        float ssum = 0.f;
        for (int r = 0; r <= u_l; ++r) ssum += kin_s[r][k];
        L_s[u_l][k] = ssum;
        if (u_l == UT - 1)
            __hip_atomic_store(&Tg[((size_t)b * NTILES + mytile) * K_ + k], ssum,
                               __ATOMIC_RELAXED, __HIP_MEMORY_SCOPE_AGENT);
    } else if (tid < 240) {
        int o = tid - 80;
        part_s[o / K_][o % K_] = 0.f;
    }
    __syncthreads();

    // ---- decoupled lookback: 16-way parallel over predecessor tiles
    if (tid < 160) {
        int jg = tid / K_, k = tid % K_;
        float sum = 0.f;
        for (int j = jg; j < mytile; j += 16) {
            const float* p = &Tg[((size_t)b * NTILES + j) * K_ + k];
            float v;
            do {
                v = __hip_atomic_load(p, __ATOMIC_RELAXED, __HIP_MEMORY_SCOPE_AGENT);
                if (!(v > 0.f)) __builtin_amdgcn_s_sleep(1);
            } while (!(v > 0.f));
            sum += v;                           // fixed per-thread order
        }
        part_s[jg][k] = sum;
    }
    __syncthreads();
    if (tid < K_) {
        float pre = 0.f;
        #pragma unroll
        for (int jg = 0; jg < 16; ++jg) pre += part_s[jg][tid];
        pre_s[tid] = pre;
    }
    __syncthreads();

    // ---- finalize kappa; per-u active-window bounds
    float lo = 1e30f, hi = -1e30f;
    if (tid < UT * K_) {
        int u_l = tid / K_, k = tid % K_;
        float kv = pre_s[k] + L_s[u_l][k];
        kin_s[u_l][k] = kv;                    // kin_s now holds kappa
        float bvv = ab_s[u_l][10 + k];
        float r = sqrtf(88.f / bvv);           // f32 exp underflow radius
        lo = kv - r; hi = kv + r;
    }
    red_lo[tid] = lo; red_hi[tid] = hi;
    __syncthreads();
    for (int s = 128; s > 0; s >>= 1) {
        if (tid < s) {
            red_lo[tid] = fminf(red_lo[tid], red_lo[tid + s]);
            red_hi[tid] = fmaxf(red_hi[tid], red_hi[tid + s]);
        }
        __syncthreads();
    }
    int t_begin = max(0, (int)floorf(red_lo[0]));
    int t_end   = min(T_, (int)ceilf(red_hi[0]) + 1);
    t_begin = (t_begin / TC) * TC;

    // ---- attend: phi + masked matmul (R8 structure)
    int u_l = tid >> 5;
    int g   = tid & 31;
    float acc4[4] = {0.f, 0.f, 0.f, 0.f};

    for (int t0 = t_begin; t0 < t_end; t0 += TC) {
        __syncthreads();
        {
            const float4* src = (const float4*)(ctx + (((size_t)b * T_ + t0) * D_));
            float4* dst = (float4*)(&ctx_s[0][0]);
            #pragma unroll
            for (int i = 0; i < (TC * D_ / 4) / 256; ++i)
                dst[tid + 256 * i] = src[tid + 256 * i];
        }
        {
            int uu = tid >> 5;
            int tl = tid & 31;
            float tf = (float)(t0 + tl);
            float ph = 0.f;
            #pragma unroll
            for (int k = 0; k < K_; ++k) {
                float d = kin_s[uu][k] - tf;
                float x = ab_s[uu][10 + k] * d * d;
                ph += ab_s[uu][k] * __expf(-x);
            }
            phi_s[uu][tl] = ph * mask[(size_t)b * T_ + t0 + tl];
        }
        __syncthreads();
        for (int tl4 = 0; tl4 < TC / 4; ++tl4) {
            float4 ph4 = *(const float4*)(&phi_s[u_l][4 * tl4]);
            #pragma unroll
            for (int qq = 0; qq < 4; ++qq) {
                float ph = (qq == 0) ? ph4.x : (qq == 1) ? ph4.y : (qq == 2) ? ph4.z : ph4.w;
                float4 c0 = ((const float4*)(&ctx_s[4 * tl4 + qq][0]))[g];
                acc4[0] += ph * c0.x; acc4[1] += ph * c0.y;
                acc4[2] += ph * c0.z; acc4[3] += ph * c0.w;
            }
        }
    }

    float* orow = out + ((size_t)(b * U_ + mytile * UT) + u_l) * D_;
    *(float4*)(orow + 4 * g) = make_float4(acc4[0], acc4[1], acc4[2], acc4[3]);
}

extern "C" void kernel_launch(void* const* d_in, const int* in_sizes, int n_in,
                              void* d_out, int out_size, void* d_ws, size_t ws_size,
                              hipStream_t stream) {
    const float* h_t  = (const float*)d_in[0];
    const float* ctx  = (const float*)d_in[1];
    const float* mask = (const float*)d_in[2];
    const float* W    = (const float*)d_in[3];
    const float* bias = (const float*)d_in[4];
    float* out = (float*)d_out;
    float* Tg = (float*)d_ws;                  // B*NTILES*K floats = 20 KB

    hipMemsetAsync(Tg, 0, (size_t)B_ * NTILES * K_ * sizeof(float), stream);
    fused_kernel<<<dim3(B_ * NTILES), dim3(256), 0, stream>>>(
        h_t, ctx, mask, W, bias, out, Tg);
}